// Round 9
// baseline (424.845 us; speedup 1.0000x reference)
//
#include <hip/hip_runtime.h>
#include <hip/hip_bf16.h>

// Problem constants (match reference)
#define NNODE_DIN 128
#define NNODE_DOUT 128
#define DEG 48
#define TOPK 32

typedef __bf16 bf16x8 __attribute__((ext_vector_type(8)));
typedef unsigned short ushortx8 __attribute__((ext_vector_type(8)));
typedef float floatx4 __attribute__((ext_vector_type(4)));

__device__ inline unsigned short f2bf(float f) {
    __bf16 h = (__bf16)f;
    return __builtin_bit_cast(unsigned short, h);
}
__device__ inline float bf2f(unsigned short u) {
    unsigned v = ((unsigned)u) << 16;
    return __builtin_bit_cast(float, v);
}

// ---------------------------------------------------------------------------
// Kernel 0: pre-swizzle W^T into split-bf16 MFMA B-fragments in wave load
// order: frag (nt,kt,lane) holds W[k][n], n = nt*16+(lane&15),
// k = kt*32+(lane>>4)*8+e. 32 KB each for hi and lo (L2-resident).
// ---------------------------------------------------------------------------
__global__ __launch_bounds__(256) void k0_wprep(
    const float* __restrict__ w, unsigned short* __restrict__ wth,
    unsigned short* __restrict__ wtl) {
    int tid = blockIdx.x * 256 + threadIdx.x;  // 0..2047
    int lane = tid & 63;
    int kt = (tid >> 6) & 3;
    int nt = tid >> 8;
    int m = lane & 15, q = lane >> 4;
    int nn = nt * 16 + m;
    int k0 = kt * 32 + q * 8;
    ushortx8 uh, ul;
#pragma unroll
    for (int e = 0; e < 8; ++e) {
        float v = w[(size_t)(k0 + e) * 128 + nn];
        unsigned short h = f2bf(v);
        uh[e] = h;
        ul[e] = f2bf(v - bf2f(h));
    }
    *(ushortx8*)(wth + tid * 8) = uh;
    *(ushortx8*)(wtl + tid * 8) = ul;
}

// ---------------------------------------------------------------------------
// Kernel 1: x = feat @ W via split-bf16 MFMA. Round-5 shape (measured best):
// one wave per 16 rows, B-frags direct from L2, transpose via 8.4 KB LDS.
// ---------------------------------------------------------------------------
__global__ __launch_bounds__(64) void k1_mfma(
    const float* __restrict__ feat, const unsigned short* __restrict__ wth,
    const unsigned short* __restrict__ wtl, unsigned short* __restrict__ xh,
    unsigned short* __restrict__ xl, int n) {
    __shared__ float s_x[16 * 132];
    int l = threadIdx.x;
    int m = l & 15, q = l >> 4;
    int r0 = blockIdx.x * 16;

    // A-fragments: feat rows r0+m, split into hi/lo bf16
    bf16x8 ah[4], al[4];
#pragma unroll
    for (int kt = 0; kt < 4; ++kt) {
        float vv[8];
        if (r0 + m < n) {
            const float* src = feat + (size_t)(r0 + m) * 128 + kt * 32 + q * 8;
            float4 v0 = *(const float4*)src;
            float4 v1 = *(const float4*)(src + 4);
            vv[0] = v0.x; vv[1] = v0.y; vv[2] = v0.z; vv[3] = v0.w;
            vv[4] = v1.x; vv[5] = v1.y; vv[6] = v1.z; vv[7] = v1.w;
        } else {
#pragma unroll
            for (int e = 0; e < 8; ++e) vv[e] = 0.0f;
        }
        ushortx8 uh, ul;
#pragma unroll
        for (int e = 0; e < 8; ++e) {
            unsigned short h = f2bf(vv[e]);
            uh[e] = h;
            ul[e] = f2bf(vv[e] - bf2f(h));
        }
        ah[kt] = __builtin_bit_cast(bf16x8, uh);
        al[kt] = __builtin_bit_cast(bf16x8, ul);
    }

    floatx4 acc[8];
#pragma unroll
    for (int nt = 0; nt < 8; ++nt) acc[nt] = (floatx4){0.f, 0.f, 0.f, 0.f};

#pragma unroll
    for (int kt = 0; kt < 4; ++kt) {
#pragma unroll
        for (int nt = 0; nt < 8; ++nt) {
            int fo = ((nt * 4 + kt) * 64 + l) * 8;
            bf16x8 bh = *(const bf16x8*)(wth + fo);
            bf16x8 bl = *(const bf16x8*)(wtl + fo);
            acc[nt] = __builtin_amdgcn_mfma_f32_16x16x32_bf16(ah[kt], bh, acc[nt], 0, 0, 0);
            acc[nt] = __builtin_amdgcn_mfma_f32_16x16x32_bf16(ah[kt], bl, acc[nt], 0, 0, 0);
            acc[nt] = __builtin_amdgcn_mfma_f32_16x16x32_bf16(al[kt], bh, acc[nt], 0, 0, 0);
        }
    }

    // D layout: acc[nt][r] = x[r0 + q*4 + r][nt*16 + m] -> transpose via LDS
#pragma unroll
    for (int nt = 0; nt < 8; ++nt)
#pragma unroll
        for (int r = 0; r < 4; ++r)
            s_x[(q * 4 + r) * 132 + nt * 16 + m] = acc[nt][r];
    __syncthreads();

#pragma unroll
    for (int rr = 0; rr < 2; ++rr) {
        int row = rr * 8 + (l >> 3);
        int c0 = (l & 7) * 16;
        if (r0 + row < n) {
            float vv[16];
#pragma unroll
            for (int j = 0; j < 4; ++j) {
                float4 v = *(const float4*)&s_x[row * 132 + c0 + j * 4];
                vv[j * 4 + 0] = v.x; vv[j * 4 + 1] = v.y;
                vv[j * 4 + 2] = v.z; vv[j * 4 + 3] = v.w;
            }
            unsigned uh[8], ul[8];
#pragma unroll
            for (int p = 0; p < 8; ++p) {
                unsigned short h0 = f2bf(vv[2 * p]);
                unsigned short h1 = f2bf(vv[2 * p + 1]);
                unsigned short l0 = f2bf(vv[2 * p] - bf2f(h0));
                unsigned short l1 = f2bf(vv[2 * p + 1] - bf2f(h1));
                uh[p] = (unsigned)h0 | ((unsigned)h1 << 16);
                ul[p] = (unsigned)l0 | ((unsigned)l1 << 16);
            }
            size_t off = (size_t)(r0 + row) * 128 + c0;
            *(uint4*)(xh + off) = make_uint4(uh[0], uh[1], uh[2], uh[3]);
            *(uint4*)(xh + off + 8) = make_uint4(uh[4], uh[5], uh[6], uh[7]);
            *(uint4*)(xl + off) = make_uint4(ul[0], ul[1], ul[2], ul[3]);
            *(uint4*)(xl + off + 8) = make_uint4(ul[4], ul[5], ul[6], ul[7]);
        }
    }
}

// ---------------------------------------------------------------------------
// Kernel 2: one wave per node, round-5 arithmetic EXACTLY, but LDS trimmed
// below 5 KB so 32 one-wave blocks fit per CU (round-5's 9.7 KB capped it at
// ~13 -> Occupancy 42%):
//   - rank via __shfl broadcast (no s_w/s_nb arrays)
//   - G reduction buffer halved via two d-passes (4224 B)
// launch_bounds(64,8) caps VGPRs at 64 (r5 compiled to 52 in this structure;
// fragments remat from L1 — they must NOT be kept live, see r6/r8 spills).
// ---------------------------------------------------------------------------
__global__ __launch_bounds__(64, 8) void k2_conv(
    const float* __restrict__ ew, const int* __restrict__ nbr,
    const float* __restrict__ bias, const unsigned short* __restrict__ xh,
    const unsigned short* __restrict__ xl, float* __restrict__ outp, int n) {
    __shared__ float s_meta[160];     // tw[32] id[32] diag[32] dist[32] omega[32]
    __shared__ float s_red[16 * 66];  // 4224 B, reused across two d-passes

    int l = threadIdx.x;
    int i = blockIdx.x;
    float* twp = &s_meta[0];
    int* idp = (int*)&s_meta[32];
    float* diag = &s_meta[64];
    float* dist = &s_meta[96];
    float* omega = &s_meta[128];

    // A+B: candidates in registers; exact top-k rank via __shfl broadcast
    {
        float wj;
        int nbj;
        if (l < DEG) {
            wj = ew[(size_t)i * DEG + l];
            nbj = nbr[(size_t)i * DEG + l];
        } else if (l == DEG) {
            wj = 1.0f;
            nbj = i;
        } else {
            wj = -1e30f;
            nbj = 0;
        }
        int rank = 0;
#pragma unroll
        for (int t2 = 0; t2 < DEG + 1; ++t2) {
            float wt = __shfl(wj, t2);
            rank += ((wt > wj) || ((wt == wj) && (t2 < l))) ? 1 : 0;
        }
        if (rank < TOPK) {
            twp[rank] = wj;
            idp[rank] = nbj;
        }
    }
    __syncthreads();

    // C: gather 16 fragments (remat from L1 in G — intended)
    int m = l & 15;
    int q = l >> 4;
    int row0 = idp[m];
    int row1 = idp[16 + m];
    const __bf16* gh0 = (const __bf16*)(xh + (size_t)row0 * 128) + q * 8;
    const __bf16* gh1 = (const __bf16*)(xh + (size_t)row1 * 128) + q * 8;
    const __bf16* gl0 = (const __bf16*)(xl + (size_t)row0 * 128) + q * 8;
    const __bf16* gl1 = (const __bf16*)(xl + (size_t)row1 * 128) + q * 8;

    bf16x8 H0[4], H1[4], L0[4], L1[4];
#pragma unroll
    for (int kt = 0; kt < 4; ++kt) {
        H0[kt] = *(const bf16x8*)(gh0 + kt * 32);
        H1[kt] = *(const bf16x8*)(gh1 + kt * 32);
        L0[kt] = *(const bf16x8*)(gl0 + kt * 32);
        L1[kt] = *(const bf16x8*)(gl1 + kt * 32);
    }

    // D: Gram = X*X^T, X ~= H + L: G = HH^T + HL^T + LH^T
    floatx4 acc[2][2];
#pragma unroll
    for (int a = 0; a < 2; ++a)
#pragma unroll
        for (int b = 0; b < 2; ++b) acc[a][b] = (floatx4){0.f, 0.f, 0.f, 0.f};

#pragma unroll
    for (int kt = 0; kt < 4; ++kt) {
        bf16x8 h0 = H0[kt], h1 = H1[kt], l0 = L0[kt], l1 = L1[kt];
        acc[0][0] = __builtin_amdgcn_mfma_f32_16x16x32_bf16(h0, h0, acc[0][0], 0, 0, 0);
        acc[0][0] = __builtin_amdgcn_mfma_f32_16x16x32_bf16(h0, l0, acc[0][0], 0, 0, 0);
        acc[0][0] = __builtin_amdgcn_mfma_f32_16x16x32_bf16(l0, h0, acc[0][0], 0, 0, 0);
        acc[0][1] = __builtin_amdgcn_mfma_f32_16x16x32_bf16(h0, h1, acc[0][1], 0, 0, 0);
        acc[0][1] = __builtin_amdgcn_mfma_f32_16x16x32_bf16(h0, l1, acc[0][1], 0, 0, 0);
        acc[0][1] = __builtin_amdgcn_mfma_f32_16x16x32_bf16(l0, h1, acc[0][1], 0, 0, 0);
        acc[1][0] = __builtin_amdgcn_mfma_f32_16x16x32_bf16(h1, h0, acc[1][0], 0, 0, 0);
        acc[1][0] = __builtin_amdgcn_mfma_f32_16x16x32_bf16(h1, l0, acc[1][0], 0, 0, 0);
        acc[1][0] = __builtin_amdgcn_mfma_f32_16x16x32_bf16(l1, h0, acc[1][0], 0, 0, 0);
        acc[1][1] = __builtin_amdgcn_mfma_f32_16x16x32_bf16(h1, h1, acc[1][1], 0, 0, 0);
        acc[1][1] = __builtin_amdgcn_mfma_f32_16x16x32_bf16(h1, l1, acc[1][1], 0, 0, 0);
        acc[1][1] = __builtin_amdgcn_mfma_f32_16x16x32_bf16(l1, h1, acc[1][1], 0, 0, 0);
    }

    // D2: diagonal (sq) from Gram so d2_aa == 0 exactly
    if (q == (m >> 2)) {
        int rd = m & 3;
        diag[m] = acc[0][0][rd];
        diag[16 + m] = acc[1][1][rd];
    }
    __syncthreads();

    // E: dist[a] = sum_b tw[b] * sqrt(d2 masked by d2>0)
#pragma unroll
    for (int ma = 0; ma < 2; ++ma) {
#pragma unroll
        for (int r = 0; r < 4; ++r) {
            int a = ma * 16 + q * 4 + r;
            float da = diag[a];
            float g0 = acc[ma][0][r];
            float g1 = acc[ma][1][r];
            float d20 = da + diag[m] - 2.0f * g0;
            float d21 = da + diag[16 + m] - 2.0f * g1;
            float t0 = (d20 > 0.0f) ? sqrtf(d20) : 0.0f;
            float t1 = (d21 > 0.0f) ? sqrtf(d21) : 0.0f;
            float v = twp[m] * t0 + twp[16 + m] * t1;
            v += __shfl_xor(v, 1);
            v += __shfl_xor(v, 2);
            v += __shfl_xor(v, 4);
            v += __shfl_xor(v, 8);
            if (m == 0) dist[a] = v;
        }
    }
    __syncthreads();

    // F: omega = exp(-dist - max(-dist)) * tw, normalized
    {
        int k32 = l & 31;
        float s = dist[k32];
        float mn = s;
        mn = fminf(mn, __shfl_xor(mn, 1));
        mn = fminf(mn, __shfl_xor(mn, 2));
        mn = fminf(mn, __shfl_xor(mn, 4));
        mn = fminf(mn, __shfl_xor(mn, 8));
        mn = fminf(mn, __shfl_xor(mn, 16));
        float e = expf(mn - s) * twp[k32];
        float sum = e;
        sum += __shfl_xor(sum, 1);
        sum += __shfl_xor(sum, 2);
        sum += __shfl_xor(sum, 4);
        sum += __shfl_xor(sum, 8);
        sum += __shfl_xor(sum, 16);
        float om = e / sum;
        if (l < 32) omega[l] = om;
    }
    __syncthreads();

    // G: two-pass (d<64, d>=64) register aggregation + m-lane LDS reduction
    {
        float w0 = omega[m];
        float w1 = omega[16 + m];
#pragma unroll
        for (int p = 0; p < 2; ++p) {
            if (p) __syncthreads();  // WAR on red reuse (1-wave: waitcnt only)
#pragma unroll
            for (int kk = 0; kk < 2; ++kk) {
                int kt = p * 2 + kk;
                float pr[8];
#pragma unroll
                for (int e = 0; e < 8; ++e) {
                    float x0 = (float)H0[kt][e] + (float)L0[kt][e];
                    float x1 = (float)H1[kt][e] + (float)L1[kt][e];
                    pr[e] = w0 * x0 + w1 * x1;
                }
                float* dst = &s_red[m * 66 + kk * 32 + q * 8];
                *(float4*)dst = make_float4(pr[0], pr[1], pr[2], pr[3]);
                *(float4*)(dst + 4) = make_float4(pr[4], pr[5], pr[6], pr[7]);
            }
            __syncthreads();
            int d = p * 64 + l;
            float o = bias[d];
#pragma unroll
            for (int mm = 0; mm < 16; ++mm) o += s_red[mm * 66 + l];
            outp[(size_t)i * 128 + d] = o;
        }
    }
}

extern "C" void kernel_launch(void* const* d_in, const int* in_sizes, int n_in,
                              void* d_out, int out_size, void* d_ws, size_t ws_size,
                              hipStream_t stream) {
    const float* feat = (const float*)d_in[0];
    const float* ew = (const float*)d_in[1];
    const float* weight = (const float*)d_in[2];
    const float* bias = (const float*)d_in[3];
    const int* nbr = (const int*)d_in[4];
    float* outp = (float*)d_out;
    int n = in_sizes[0] / NNODE_DIN;  // 50000

    unsigned short* xh = (unsigned short*)d_ws;            // n x 128 bf16
    unsigned short* xl = xh + (size_t)n * NNODE_DOUT;      // n x 128 bf16
    unsigned short* wth = xl + (size_t)n * NNODE_DOUT;     // 2048 frags x 16B
    unsigned short* wtl = wth + 2048 * 8;

    hipLaunchKernelGGL(k0_wprep, dim3(8), dim3(256), 0, stream, weight, wth, wtl);
    int grid1 = (n + 15) / 16;
    hipLaunchKernelGGL(k1_mfma, dim3(grid1), dim3(64), 0, stream, feat, wth, wtl, xh, xl, n);
    hipLaunchKernelGGL(k2_conv, dim3(n), dim3(64), 0, stream, ew, nbr, bias, xh, xl, outp, n);
}

// Round 10
// 246.396 us; speedup vs baseline: 1.7242x; 1.7242x over previous
//
#include <hip/hip_runtime.h>
#include <hip/hip_bf16.h>

// Problem constants (match reference)
#define NNODE_DIN 128
#define NNODE_DOUT 128
#define DEG 48
#define TOPK 32

typedef __bf16 bf16x8 __attribute__((ext_vector_type(8)));
typedef unsigned short ushortx8 __attribute__((ext_vector_type(8)));
typedef float floatx4 __attribute__((ext_vector_type(4)));

__device__ inline unsigned short f2bf(float f) {
    __bf16 h = (__bf16)f;
    return __builtin_bit_cast(unsigned short, h);
}
__device__ inline float bf2f(unsigned short u) {
    unsigned v = ((unsigned)u) << 16;
    return __builtin_bit_cast(float, v);
}

// ---------------------------------------------------------------------------
// Kernel 0: pre-swizzle W^T into split-bf16 MFMA B-fragments in wave load
// order: frag (nt,kt,lane) holds W[k][n], n = nt*16+(lane&15),
// k = kt*32+(lane>>4)*8+e. 32 KB each for hi and lo (L2-resident).
// ---------------------------------------------------------------------------
__global__ __launch_bounds__(256) void k0_wprep(
    const float* __restrict__ w, unsigned short* __restrict__ wth,
    unsigned short* __restrict__ wtl) {
    int tid = blockIdx.x * 256 + threadIdx.x;  // 0..2047
    int lane = tid & 63;
    int kt = (tid >> 6) & 3;
    int nt = tid >> 8;
    int m = lane & 15, q = lane >> 4;
    int nn = nt * 16 + m;
    int k0 = kt * 32 + q * 8;
    ushortx8 uh, ul;
#pragma unroll
    for (int e = 0; e < 8; ++e) {
        float v = w[(size_t)(k0 + e) * 128 + nn];
        unsigned short h = f2bf(v);
        uh[e] = h;
        ul[e] = f2bf(v - bf2f(h));
    }
    *(ushortx8*)(wth + tid * 8) = uh;
    *(ushortx8*)(wtl + tid * 8) = ul;
}

// ---------------------------------------------------------------------------
// Kernel 1: x = feat @ W via split-bf16 MFMA. Round-5 shape (measured best):
// one wave per 16 rows, B-frags direct from L2, transpose via 8.4 KB LDS.
// ---------------------------------------------------------------------------
__global__ __launch_bounds__(64) void k1_mfma(
    const float* __restrict__ feat, const unsigned short* __restrict__ wth,
    const unsigned short* __restrict__ wtl, unsigned short* __restrict__ xh,
    unsigned short* __restrict__ xl, int n) {
    __shared__ float s_x[16 * 132];
    int l = threadIdx.x;
    int m = l & 15, q = l >> 4;
    int r0 = blockIdx.x * 16;

    // A-fragments: feat rows r0+m, split into hi/lo bf16
    bf16x8 ah[4], al[4];
#pragma unroll
    for (int kt = 0; kt < 4; ++kt) {
        float vv[8];
        if (r0 + m < n) {
            const float* src = feat + (size_t)(r0 + m) * 128 + kt * 32 + q * 8;
            float4 v0 = *(const float4*)src;
            float4 v1 = *(const float4*)(src + 4);
            vv[0] = v0.x; vv[1] = v0.y; vv[2] = v0.z; vv[3] = v0.w;
            vv[4] = v1.x; vv[5] = v1.y; vv[6] = v1.z; vv[7] = v1.w;
        } else {
#pragma unroll
            for (int e = 0; e < 8; ++e) vv[e] = 0.0f;
        }
        ushortx8 uh, ul;
#pragma unroll
        for (int e = 0; e < 8; ++e) {
            unsigned short h = f2bf(vv[e]);
            uh[e] = h;
            ul[e] = f2bf(vv[e] - bf2f(h));
        }
        ah[kt] = __builtin_bit_cast(bf16x8, uh);
        al[kt] = __builtin_bit_cast(bf16x8, ul);
    }

    floatx4 acc[8];
#pragma unroll
    for (int nt = 0; nt < 8; ++nt) acc[nt] = (floatx4){0.f, 0.f, 0.f, 0.f};

#pragma unroll
    for (int kt = 0; kt < 4; ++kt) {
#pragma unroll
        for (int nt = 0; nt < 8; ++nt) {
            int fo = ((nt * 4 + kt) * 64 + l) * 8;
            bf16x8 bh = *(const bf16x8*)(wth + fo);
            bf16x8 bl = *(const bf16x8*)(wtl + fo);
            acc[nt] = __builtin_amdgcn_mfma_f32_16x16x32_bf16(ah[kt], bh, acc[nt], 0, 0, 0);
            acc[nt] = __builtin_amdgcn_mfma_f32_16x16x32_bf16(ah[kt], bl, acc[nt], 0, 0, 0);
            acc[nt] = __builtin_amdgcn_mfma_f32_16x16x32_bf16(al[kt], bh, acc[nt], 0, 0, 0);
        }
    }

    // D layout: acc[nt][r] = x[r0 + q*4 + r][nt*16 + m] -> transpose via LDS
#pragma unroll
    for (int nt = 0; nt < 8; ++nt)
#pragma unroll
        for (int r = 0; r < 4; ++r)
            s_x[(q * 4 + r) * 132 + nt * 16 + m] = acc[nt][r];
    __syncthreads();

#pragma unroll
    for (int rr = 0; rr < 2; ++rr) {
        int row = rr * 8 + (l >> 3);
        int c0 = (l & 7) * 16;
        if (r0 + row < n) {
            float vv[16];
#pragma unroll
            for (int j = 0; j < 4; ++j) {
                float4 v = *(const float4*)&s_x[row * 132 + c0 + j * 4];
                vv[j * 4 + 0] = v.x; vv[j * 4 + 1] = v.y;
                vv[j * 4 + 2] = v.z; vv[j * 4 + 3] = v.w;
            }
            unsigned uh[8], ul[8];
#pragma unroll
            for (int p = 0; p < 8; ++p) {
                unsigned short h0 = f2bf(vv[2 * p]);
                unsigned short h1 = f2bf(vv[2 * p + 1]);
                unsigned short l0 = f2bf(vv[2 * p] - bf2f(h0));
                unsigned short l1 = f2bf(vv[2 * p + 1] - bf2f(h1));
                uh[p] = (unsigned)h0 | ((unsigned)h1 << 16);
                ul[p] = (unsigned)l0 | ((unsigned)l1 << 16);
            }
            size_t off = (size_t)(r0 + row) * 128 + c0;
            *(uint4*)(xh + off) = make_uint4(uh[0], uh[1], uh[2], uh[3]);
            *(uint4*)(xh + off + 8) = make_uint4(uh[4], uh[5], uh[6], uh[7]);
            *(uint4*)(xl + off) = make_uint4(ul[0], ul[1], ul[2], ul[3]);
            *(uint4*)(xl + off + 8) = make_uint4(ul[4], ul[5], ul[6], ul[7]);
        }
    }
}

// ---------------------------------------------------------------------------
// Kernel 2: one wave per node, round-5 arithmetic EXACTLY, LDS trimmed to
// 5120 B (shfl-based rank, halved two-pass s_red) -> 32 blocks/CU static.
// launch_bounds(64,4): 128-VGPR cap. (64,8) in round 9 capped at 64 VGPRs
// and spilled (VGPR 32, WRITE 737 MB); this structure needs the ~52-VGPR
// r5 allocation, which only materializes under the 128 cap. Occupancy is
// then governed by actual usage (512/52 -> 8 waves/SIMD possible) and LDS.
// ---------------------------------------------------------------------------
__global__ __launch_bounds__(64, 4) void k2_conv(
    const float* __restrict__ ew, const int* __restrict__ nbr,
    const float* __restrict__ bias, const unsigned short* __restrict__ xh,
    const unsigned short* __restrict__ xl, float* __restrict__ outp, int n) {
    __shared__ float s_meta[160];     // tw[32] id[32] diag[32] dist[32] omega[32]
    __shared__ float s_red[16 * 66];  // 4224 B, reused across two d-passes

    int l = threadIdx.x;
    int i = blockIdx.x;
    float* twp = &s_meta[0];
    int* idp = (int*)&s_meta[32];
    float* diag = &s_meta[64];
    float* dist = &s_meta[96];
    float* omega = &s_meta[128];

    // A+B: candidates in registers; exact top-k rank via __shfl broadcast
    {
        float wj;
        int nbj;
        if (l < DEG) {
            wj = ew[(size_t)i * DEG + l];
            nbj = nbr[(size_t)i * DEG + l];
        } else if (l == DEG) {
            wj = 1.0f;
            nbj = i;
        } else {
            wj = -1e30f;
            nbj = 0;
        }
        int rank = 0;
#pragma unroll
        for (int t2 = 0; t2 < DEG + 1; ++t2) {
            float wt = __shfl(wj, t2);
            rank += ((wt > wj) || ((wt == wj) && (t2 < l))) ? 1 : 0;
        }
        if (rank < TOPK) {
            twp[rank] = wj;
            idp[rank] = nbj;
        }
    }
    __syncthreads();

    // C: gather 16 fragments (remat from L1 in G — intended)
    int m = l & 15;
    int q = l >> 4;
    int row0 = idp[m];
    int row1 = idp[16 + m];
    const __bf16* gh0 = (const __bf16*)(xh + (size_t)row0 * 128) + q * 8;
    const __bf16* gh1 = (const __bf16*)(xh + (size_t)row1 * 128) + q * 8;
    const __bf16* gl0 = (const __bf16*)(xl + (size_t)row0 * 128) + q * 8;
    const __bf16* gl1 = (const __bf16*)(xl + (size_t)row1 * 128) + q * 8;

    bf16x8 H0[4], H1[4], L0[4], L1[4];
#pragma unroll
    for (int kt = 0; kt < 4; ++kt) {
        H0[kt] = *(const bf16x8*)(gh0 + kt * 32);
        H1[kt] = *(const bf16x8*)(gh1 + kt * 32);
        L0[kt] = *(const bf16x8*)(gl0 + kt * 32);
        L1[kt] = *(const bf16x8*)(gl1 + kt * 32);
    }

    // D: Gram = X*X^T, X ~= H + L: G = HH^T + HL^T + LH^T
    floatx4 acc[2][2];
#pragma unroll
    for (int a = 0; a < 2; ++a)
#pragma unroll
        for (int b = 0; b < 2; ++b) acc[a][b] = (floatx4){0.f, 0.f, 0.f, 0.f};

#pragma unroll
    for (int kt = 0; kt < 4; ++kt) {
        bf16x8 h0 = H0[kt], h1 = H1[kt], l0 = L0[kt], l1 = L1[kt];
        acc[0][0] = __builtin_amdgcn_mfma_f32_16x16x32_bf16(h0, h0, acc[0][0], 0, 0, 0);
        acc[0][0] = __builtin_amdgcn_mfma_f32_16x16x32_bf16(h0, l0, acc[0][0], 0, 0, 0);
        acc[0][0] = __builtin_amdgcn_mfma_f32_16x16x32_bf16(l0, h0, acc[0][0], 0, 0, 0);
        acc[0][1] = __builtin_amdgcn_mfma_f32_16x16x32_bf16(h0, h1, acc[0][1], 0, 0, 0);
        acc[0][1] = __builtin_amdgcn_mfma_f32_16x16x32_bf16(h0, l1, acc[0][1], 0, 0, 0);
        acc[0][1] = __builtin_amdgcn_mfma_f32_16x16x32_bf16(l0, h1, acc[0][1], 0, 0, 0);
        acc[1][0] = __builtin_amdgcn_mfma_f32_16x16x32_bf16(h1, h0, acc[1][0], 0, 0, 0);
        acc[1][0] = __builtin_amdgcn_mfma_f32_16x16x32_bf16(h1, l0, acc[1][0], 0, 0, 0);
        acc[1][0] = __builtin_amdgcn_mfma_f32_16x16x32_bf16(l1, h0, acc[1][0], 0, 0, 0);
        acc[1][1] = __builtin_amdgcn_mfma_f32_16x16x32_bf16(h1, h1, acc[1][1], 0, 0, 0);
        acc[1][1] = __builtin_amdgcn_mfma_f32_16x16x32_bf16(h1, l1, acc[1][1], 0, 0, 0);
        acc[1][1] = __builtin_amdgcn_mfma_f32_16x16x32_bf16(l1, h1, acc[1][1], 0, 0, 0);
    }

    // D2: diagonal (sq) from Gram so d2_aa == 0 exactly
    if (q == (m >> 2)) {
        int rd = m & 3;
        diag[m] = acc[0][0][rd];
        diag[16 + m] = acc[1][1][rd];
    }
    __syncthreads();

    // E: dist[a] = sum_b tw[b] * sqrt(d2 masked by d2>0)
#pragma unroll
    for (int ma = 0; ma < 2; ++ma) {
#pragma unroll
        for (int r = 0; r < 4; ++r) {
            int a = ma * 16 + q * 4 + r;
            float da = diag[a];
            float g0 = acc[ma][0][r];
            float g1 = acc[ma][1][r];
            float d20 = da + diag[m] - 2.0f * g0;
            float d21 = da + diag[16 + m] - 2.0f * g1;
            float t0 = (d20 > 0.0f) ? sqrtf(d20) : 0.0f;
            float t1 = (d21 > 0.0f) ? sqrtf(d21) : 0.0f;
            float v = twp[m] * t0 + twp[16 + m] * t1;
            v += __shfl_xor(v, 1);
            v += __shfl_xor(v, 2);
            v += __shfl_xor(v, 4);
            v += __shfl_xor(v, 8);
            if (m == 0) dist[a] = v;
        }
    }
    __syncthreads();

    // F: omega = exp(-dist - max(-dist)) * tw, normalized
    {
        int k32 = l & 31;
        float s = dist[k32];
        float mn = s;
        mn = fminf(mn, __shfl_xor(mn, 1));
        mn = fminf(mn, __shfl_xor(mn, 2));
        mn = fminf(mn, __shfl_xor(mn, 4));
        mn = fminf(mn, __shfl_xor(mn, 8));
        mn = fminf(mn, __shfl_xor(mn, 16));
        float e = expf(mn - s) * twp[k32];
        float sum = e;
        sum += __shfl_xor(sum, 1);
        sum += __shfl_xor(sum, 2);
        sum += __shfl_xor(sum, 4);
        sum += __shfl_xor(sum, 8);
        sum += __shfl_xor(sum, 16);
        float om = e / sum;
        if (l < 32) omega[l] = om;
    }
    __syncthreads();

    // G: two-pass (d<64, d>=64) register aggregation + m-lane LDS reduction
    {
        float w0 = omega[m];
        float w1 = omega[16 + m];
#pragma unroll
        for (int p = 0; p < 2; ++p) {
            if (p) __syncthreads();  // WAR on red reuse (1-wave: waitcnt only)
#pragma unroll
            for (int kk = 0; kk < 2; ++kk) {
                int kt = p * 2 + kk;
                float pr[8];
#pragma unroll
                for (int e = 0; e < 8; ++e) {
                    float x0 = (float)H0[kt][e] + (float)L0[kt][e];
                    float x1 = (float)H1[kt][e] + (float)L1[kt][e];
                    pr[e] = w0 * x0 + w1 * x1;
                }
                float* dst = &s_red[m * 66 + kk * 32 + q * 8];
                *(float4*)dst = make_float4(pr[0], pr[1], pr[2], pr[3]);
                *(float4*)(dst + 4) = make_float4(pr[4], pr[5], pr[6], pr[7]);
            }
            __syncthreads();
            int d = p * 64 + l;
            float o = bias[d];
#pragma unroll
            for (int mm = 0; mm < 16; ++mm) o += s_red[mm * 66 + l];
            outp[(size_t)i * 128 + d] = o;
        }
    }
}

extern "C" void kernel_launch(void* const* d_in, const int* in_sizes, int n_in,
                              void* d_out, int out_size, void* d_ws, size_t ws_size,
                              hipStream_t stream) {
    const float* feat = (const float*)d_in[0];
    const float* ew = (const float*)d_in[1];
    const float* weight = (const float*)d_in[2];
    const float* bias = (const float*)d_in[3];
    const int* nbr = (const int*)d_in[4];
    float* outp = (float*)d_out;
    int n = in_sizes[0] / NNODE_DIN;  // 50000

    unsigned short* xh = (unsigned short*)d_ws;            // n x 128 bf16
    unsigned short* xl = xh + (size_t)n * NNODE_DOUT;      // n x 128 bf16
    unsigned short* wth = xl + (size_t)n * NNODE_DOUT;     // 2048 frags x 16B
    unsigned short* wtl = wth + 2048 * 8;

    hipLaunchKernelGGL(k0_wprep, dim3(8), dim3(256), 0, stream, weight, wth, wtl);
    int grid1 = (n + 15) / 16;
    hipLaunchKernelGGL(k1_mfma, dim3(grid1), dim3(64), 0, stream, feat, wth, wtl, xh, xl, n);
    hipLaunchKernelGGL(k2_conv, dim3(n), dim3(64), 0, stream, ew, nbr, bias, xh, xl, outp, n);
}